// Round 2
// baseline (163.592 us; speedup 1.0000x reference)
//
#include <hip/hip_runtime.h>
#include <math.h>

// CellList dense masked-distance map, N=6144, no PBC.
// out[i*N+j] = |r_i - r_j| if (i>j && species_i!=-1 && species_j!=-1 &&
//                              dist<=cutoff && sq>0) else 0.
//
// R7 = TWO-PHASE split. R6 (fused zero+compute, 60 us kernel-side) ran its
// dense stores at only ~2.5 TB/s while the harness's own fillBuffer hits
// 6.5 TB/s on the SAME volume: pure-store waves with deep store queues
// stream at peak; stores interleaved with compute don't. So:
//   Phase 1: pure zero-fill of all 151 MB, fill-shaped (16 independent
//            contiguous dwordx4 stores/thread) -> ~24 us at fill BW.
//   Phase 2: compute-only over lower-tri 128x128 tiles; store ONLY the
//            ~0.8% of pairs that pass the cutoff (~0.6 MB scattered
//            dwords, exec-masked, s_cbranch_execz skips empty groups).
// Same-stream dispatch order + inter-kernel release/acquire makes the
// overwrite-zeros-with-hits ordering safe.
//  - mask via sq <= T (T = largest f32 with sqrt_rn(T) <= cutoff) -- bit-
//    exact vs reference (absmax 0.0 in prior rounds).
//  - dist via raw v_sqrt_f32 (absmax 0.0 previously; threshold 0.1).
//  - sq in numpy's ((x*x + y*y) + z*z) order, no FMA contraction.
//  - sq>0 omitted: coincident atoms give sqrt(0)=0 == masked 0, value-exact.

constexpr int N = 6144;

// ---------------- Phase 1: zero fill ----------------
constexpr int ZBLOCKS = 2304;                 // 9 blocks/CU
constexpr int ZTHREADS = 256;
constexpr int ZTOTAL4 = N * N / 4;            // 9,437,184 float4
constexpr int ZPT = ZTOTAL4 / (ZBLOCKS * ZTHREADS);  // 16 float4/thread

__global__ __launch_bounds__(ZTHREADS) void zero_kernel(float4* __restrict__ out4)
{
    const size_t idx = (size_t)blockIdx.x * ZTHREADS + threadIdx.x;
    const float4 z = make_float4(0.f, 0.f, 0.f, 0.f);
    const size_t stride = (size_t)ZBLOCKS * ZTHREADS;
#pragma unroll
    for (int q = 0; q < ZPT; ++q)
        out4[idx + (size_t)q * stride] = z;
}

// ---------------- Phase 2: sparse compute ----------------
constexpr int TILE  = 128;                    // 128x128 pair tile
constexpr int NT    = N / TILE;               // 48 tiles per dim

__global__ __launch_bounds__(256) void pair_kernel(
    const float* __restrict__ coords,   // [N][3] f32
    const int*   __restrict__ species,  // [N] i32
    const int*   __restrict__ cutoff_p, // [1] i32
    float*       __restrict__ out)      // [N][N] f32
{
    const int tj = blockIdx.x;   // j tile (columns)
    const int ti = blockIdx.y;   // i tile (rows)
    if (ti < tj) return;         // upper-tri tiles: nothing to do

    // T = largest f32 x with sqrt_rn(x) <= c (see header comment).
    const float  c  = (float)cutoff_p[0];
    const float  cn = __int_as_float(__float_as_int(c) + 1);
    const double md = (double)c + 0.5 * ((double)cn - (double)c);
    const double Td = md * md;
    float T = (float)Td;
    if ((double)T > Td) T = __int_as_float(__float_as_int(T) - 1);

    __shared__ float4 ilds[TILE];  // {x, y, z, bitcast(species)}

    const int t  = (int)threadIdx.x;
    const int jl = t & (TILE - 1);     // 0..127: this thread's j column
    const int ih = t >> 7;             // 0/1: which 64-row half this thread scans

    // Stage i-side tile (coords + species) into LDS.
    if (t < TILE) {
        const int i = ti * TILE + t;
        ilds[t] = make_float4(coords[3 * i + 0], coords[3 * i + 1],
                              coords[3 * i + 2], __int_as_float(species[i]));
    }

    // j-side data lives in registers for the whole block.
    const int   j  = tj * TILE + jl;
    const float xj = coords[3 * j + 0];
    const float yj = coords[3 * j + 1];
    const float zj = coords[3 * j + 2];
    const bool  jok = (species[j] != -1);

    __syncthreads();

    const int il0 = ih * 64;
#pragma unroll 4
    for (int q = 0; q < 64; ++q) {
        const int il = il0 + q;
        const float4 ic = ilds[il];           // broadcast read, conflict-free
        const int    i  = ti * TILE + il;
        // Exact numpy order: (dx*dx + dy*dy) + dz*dz, no FMA.
        const float dx = __fsub_rn(ic.x, xj);
        const float dy = __fsub_rn(ic.y, yj);
        const float dz = __fsub_rn(ic.z, zj);
        const float sq = __fadd_rn(
            __fadd_rn(__fmul_rn(dx, dx), __fmul_rn(dy, dy)),
            __fmul_rn(dz, dz));
        const bool m = (sq <= T) && jok &&
                       (__float_as_int(ic.w) != -1) && (j < i);
        if (m)
            out[(size_t)i * N + j] = __builtin_amdgcn_sqrtf(sq);
    }
}

extern "C" void kernel_launch(void* const* d_in, const int* in_sizes, int n_in,
                              void* d_out, int out_size, void* d_ws, size_t ws_size,
                              hipStream_t stream) {
    // setup_inputs() order: species (i32 [1,N]), coordinates (f32 [1,N,3]),
    // cutoff (python int -> i32 [1]).
    const int*   species = (const int*)d_in[0];
    const float* coords  = (const float*)d_in[1];
    const int*   cutoff  = (const int*)d_in[2];
    float*       out     = (float*)d_out;

    hipLaunchKernelGGL(zero_kernel, dim3(ZBLOCKS), dim3(ZTHREADS), 0, stream,
                       reinterpret_cast<float4*>(out));
    hipLaunchKernelGGL(pair_kernel, dim3(NT, NT), dim3(256), 0, stream,
                       coords, species, cutoff, out);
}

// Round 3
// 155.337 us; speedup vs baseline: 1.0531x; 1.0531x over previous
//
#include <hip/hip_runtime.h>
#include <math.h>

// CellList dense masked-distance map, N=6144, no PBC.
// out[i*N+j] = |r_i - r_j| if (i>j && species_i!=-1 && species_j!=-1 &&
//                              dist<=cutoff && sq>0) else 0.
//
// R8 = R6 fused structure + BATCHED STORES. R7's two-phase split regressed
// (68 us slice vs R6's 62): serializing the 151 MB zero-fill removed the
// compute/store overlap the fused kernel got for free. The surviving
// theory from the fill-vs-us gap (6.5 vs 2.5 TB/s) is store-queue DEPTH:
// the fill issues 16 independent back-to-back dwordx4/thread; R6 issued 2,
// fenced by ~80 VALU + scalar loads + a branch per row. R8 computes all
// 6 rows into registers first, then issues all 12 float4 stores
// back-to-back (sched_barrier pins the grouping).
//  - 3072 blocks (12/CU); each block = one 2048-col strip x 6 consecutive
//    rows. j-side coords/species loaded ONCE per thread, reused across the
//    6 rows. Lane-contiguous store chunks (tid*4, +1024).
//  - upper-triangle / dummy rows: result regs stay zero, stored in batch.
//  - mask via sq <= T (T = largest f32 with sqrt_rn(T) <= cutoff) -- bit-
//    exact vs reference (absmax 0.0 in R2/R4/R6/R7).
//  - dist via raw v_sqrt_f32 (1 ulp; threshold 0.1).
//  - sq in numpy's ((x*x + y*y) + z*z) order, no FMA contraction.

constexpr int N      = 6144;
constexpr int BLOCK  = 256;
constexpr int CPB    = 2048;         // columns per block
constexpr int HALF   = CPB / 2;      // 1024: two contiguous 4-col chunks/thread
constexpr int NSTRIP = N / CPB;      // 3 column strips
constexpr int RPB    = 6;            // rows per block
constexpr int NROWG  = N / RPB;      // 1024 row groups

__global__ __launch_bounds__(BLOCK) void cell_list_kernel(
    const float* __restrict__ coords,   // [N][3] f32
    const int*   __restrict__ species,  // [N] i32
    const int*   __restrict__ cutoff_p, // [1] i32
    float*       __restrict__ out)      // [N][N] f32
{
    const int bx    = blockIdx.x;
    const int strip = bx % NSTRIP;
    const int i0    = (bx / NSTRIP) * RPB;
    const int base  = strip * CPB;
    const int jA    = base + (int)threadIdx.x * 4;  // chunk A: contiguous across wave
    const int jB    = jA + HALF;                    // chunk B: contiguous across wave

    // T = largest f32 x with sqrt_rn(x) <= c: sqrt_rn(x) <= c iff
    // sqrt_exact(x) < c + 0.5*ulp(c) (tie impossible: midpoint^2 not f32-
    // representable). Exact in double, rounded down. Scalar, once.
    const float  c  = (float)cutoff_p[0];
    const float  cn = __int_as_float(__float_as_int(c) + 1);
    const double md = (double)c + 0.5 * ((double)cn - (double)c);
    const double Td = md * md;
    float T = (float)Td;
    if ((double)T > Td) T = __int_as_float(__float_as_int(T) - 1);

    // Load j-side data once per thread iff any row in this block computes.
    float fA[12], fB[12];
    int   sA[4],  sB[4];
    const bool anyrow = (i0 + RPB - 1 > base);
    if (anyrow) {
        const float4* ca = reinterpret_cast<const float4*>(coords + 3 * (size_t)jA);
        const float4* cb = reinterpret_cast<const float4*>(coords + 3 * (size_t)jB);
#pragma unroll
        for (int q = 0; q < 3; ++q) {
            const float4 va = ca[q];
            fA[4 * q + 0] = va.x; fA[4 * q + 1] = va.y;
            fA[4 * q + 2] = va.z; fA[4 * q + 3] = va.w;
            const float4 vb = cb[q];
            fB[4 * q + 0] = vb.x; fB[4 * q + 1] = vb.y;
            fB[4 * q + 2] = vb.z; fB[4 * q + 3] = vb.w;
        }
        const int4 sa = *reinterpret_cast<const int4*>(species + jA);
        const int4 sb = *reinterpret_cast<const int4*>(species + jB);
        sA[0] = sa.x; sA[1] = sa.y; sA[2] = sa.z; sA[3] = sa.w;
        sB[0] = sb.x; sB[1] = sb.y; sB[2] = sb.z; sB[3] = sb.w;
    }

    // Compute all 6 rows into registers.
    float rA[RPB][4], rB[RPB][4];
#pragma unroll
    for (int rr = 0; rr < RPB; ++rr)
#pragma unroll
        for (int k = 0; k < 4; ++k) { rA[rr][k] = 0.0f; rB[rr][k] = 0.0f; }

#pragma unroll
    for (int rr = 0; rr < RPB; ++rr) {
        const int i = i0 + rr;
        if (i <= base) continue;            // whole strip j >= i: stay zero
        const int si = species[i];          // block-uniform -> scalar load
        if (si == -1) continue;             // dummy row: stay zero

        const float xi = coords[3 * i + 0];
        const float yi = coords[3 * i + 1];
        const float zi = coords[3 * i + 2];

#pragma unroll
        for (int k = 0; k < 4; ++k) {
            // Exact numpy order: (dx*dx + dy*dy) + dz*dz, no FMA.
            {
                const float dx = __fsub_rn(xi, fA[3 * k + 0]);
                const float dy = __fsub_rn(yi, fA[3 * k + 1]);
                const float dz = __fsub_rn(zi, fA[3 * k + 2]);
                const float sq = __fadd_rn(
                    __fadd_rn(__fmul_rn(dx, dx), __fmul_rn(dy, dy)),
                    __fmul_rn(dz, dz));
                const bool m = (sq <= T) && (sA[k] != -1) && (jA + k < i);
                rA[rr][k] = m ? __builtin_amdgcn_sqrtf(sq) : 0.0f;
            }
            {
                const float dx = __fsub_rn(xi, fB[3 * k + 0]);
                const float dy = __fsub_rn(yi, fB[3 * k + 1]);
                const float dz = __fsub_rn(zi, fB[3 * k + 2]);
                const float sq = __fadd_rn(
                    __fadd_rn(__fmul_rn(dx, dx), __fmul_rn(dy, dy)),
                    __fmul_rn(dz, dz));
                const bool m = (sq <= T) && (sB[k] != -1) && (jB + k < i);
                rB[rr][k] = m ? __builtin_amdgcn_sqrtf(sq) : 0.0f;
            }
        }
    }

    // Pin the compute/store grouping: all 12 stores issue back-to-back,
    // fill-style, building store-queue depth.
    __builtin_amdgcn_sched_barrier(0);

#pragma unroll
    for (int rr = 0; rr < RPB; ++rr) {
        const int i = i0 + rr;
        float4* ovA = reinterpret_cast<float4*>(out + (size_t)i * N + jA);
        float4* ovB = reinterpret_cast<float4*>(out + (size_t)i * N + jB);
        *ovA = make_float4(rA[rr][0], rA[rr][1], rA[rr][2], rA[rr][3]);
        *ovB = make_float4(rB[rr][0], rB[rr][1], rB[rr][2], rB[rr][3]);
    }
}

extern "C" void kernel_launch(void* const* d_in, const int* in_sizes, int n_in,
                              void* d_out, int out_size, void* d_ws, size_t ws_size,
                              hipStream_t stream) {
    // setup_inputs() order: species (i32 [1,N]), coordinates (f32 [1,N,3]),
    // cutoff (python int -> i32 [1]).
    const int*   species = (const int*)d_in[0];
    const float* coords  = (const float*)d_in[1];
    const int*   cutoff  = (const int*)d_in[2];
    float*       out     = (float*)d_out;

    dim3 block(BLOCK);
    dim3 grid(NSTRIP * NROWG);  // 3072 blocks = 12/CU
    hipLaunchKernelGGL(cell_list_kernel, grid, block, 0, stream,
                       coords, species, cutoff, out);
}